// Round 4
// baseline (372.610 us; speedup 1.0000x reference)
//
#include <hip/hip_runtime.h>

// FrameFiberConv as bf16 MFMA GEMM (pure bf16: error ~1e-2 << 0.12 threshold).
//   z[v, n=f*16+i] = sum_k x[v, k=d*16+c] * WT[n][k],  WT[n][k] = K[(d-i)&15, c, f]
//   out[v,f] = relu(max_i z[v,f*16+i] + bias[f])

typedef __attribute__((ext_vector_type(8))) short  bf16x8;
typedef __attribute__((ext_vector_type(4))) float  f32x4;

struct us4 { unsigned short a, b, c, d; };

__device__ __forceinline__ unsigned short f32_to_bf16(float f) {
    unsigned int u = __builtin_bit_cast(unsigned int, f);
    u += 0x7FFFu + ((u >> 16) & 1u);            // round-to-nearest-even
    return (unsigned short)(u >> 16);
}

// ---- kernel 1: build WT bf16 into ws (WH[256][256]) ----
__global__ __launch_bounds__(256) void build_wt(
    const float* __restrict__ kern,             // [16][16][16] (w,c,f)
    unsigned short* __restrict__ wh)
{
    int n = blockIdx.x;                         // n = f*16 + i
    int k = threadIdx.x;                        // k = d*16 + c
    int f = n >> 4, i = n & 15;
    int d = k >> 4, c = k & 15;
    int w = (d - i) & 15;
    wh[(n << 8) + k] = f32_to_bf16(kern[(w << 8) + (c << 4) + f]);
}

// ---- kernel 2: main GEMM + fused max/bias/relu ----
// Block: 512 thr (8 waves, 4 row-waves x 2 col-waves). Tile BM=128, N=256, BK=64.
// LDS swizzle (ushort idx): si = r*64 + (kk ^ ((r&7)<<3))  -- kills 128B-stride
// bank conflicts on the 16-lane row-slice ds_read_b128 (G4).
__global__ __launch_bounds__(512) void ffconv_mfma(
    const float* __restrict__ x,                // [M][256]
    const unsigned short* __restrict__ wh_g,    // [256][256] bf16
    const float* __restrict__ bias,             // [16]
    float* __restrict__ out,                    // [M][16]
    int M)
{
    __shared__ unsigned short XH[128 * 64];     // 16 KB
    __shared__ unsigned short WH[256 * 64];     // 32 KB
    __shared__ float OUTS[128 * 16];            // 8 KB

    const int tid  = threadIdx.x;
    const int lane = tid & 63;
    const int wid  = tid >> 6;
    const int wm   = wid >> 1;                  // 0..3: rows 32*wm..+32
    const int wn   = wid & 1;                   // 0..1: cols 128*wn..+128
    const int l15  = lane & 15;
    const int l4   = lane >> 4;
    const int v0   = blockIdx.x * 128;

    f32x4 acc[2][8];
    #pragma unroll
    for (int rm = 0; rm < 2; ++rm)
        #pragma unroll
        for (int cn = 0; cn < 8; ++cn)
            acc[rm][cn] = (f32x4){0.f, 0.f, 0.f, 0.f};

    for (int kc = 0; kc < 4; ++kc) {
        if (kc > 0) __syncthreads();            // prev compute done before overwrite

        // ---- stage x chunk: [128 rows][64 k] fp32 -> bf16, swizzled ----
        #pragma unroll
        for (int q = 0; q < 4; ++q) {
            int e  = (q * 512 + tid) * 4;       // element in chunk (0..8191)
            int r  = e >> 6;
            int kk = e & 63;
            float4 xv = {0.f, 0.f, 0.f, 0.f};
            if (v0 + r < M)
                xv = *reinterpret_cast<const float4*>(
                    x + (size_t)(v0 + r) * 256 + kc * 64 + kk);
            us4 h;
            h.a = f32_to_bf16(xv.x);
            h.b = f32_to_bf16(xv.y);
            h.c = f32_to_bf16(xv.z);
            h.d = f32_to_bf16(xv.w);
            int si = r * 64 + (kk ^ ((r & 7) << 3));
            *reinterpret_cast<us4*>(XH + si) = h;
        }

        // ---- stage W chunk: [256 n][64 k] bf16, swizzled (FULL n range) ----
        #pragma unroll
        for (int q = 0; q < 8; ++q) {
            int e  = (q * 512 + tid) * 4;       // 0..16383
            int n  = e >> 6;                    // 0..255
            int kk = e & 63;
            us4 vh = *reinterpret_cast<const us4*>(
                wh_g + (size_t)n * 256 + kc * 64 + kk);
            int sj = n * 64 + (kk ^ ((n & 7) << 3));
            *reinterpret_cast<us4*>(WH + sj) = vh;
        }

        __syncthreads();

        // ---- compute: 2 k-steps of 32 ----
        #pragma unroll
        for (int ks = 0; ks < 2; ++ks) {
            int kb = ks * 32 + l4 * 8;          // this lane's k-octet in chunk
            bf16x8 ah[2];
            #pragma unroll
            for (int rm = 0; rm < 2; ++rm) {
                int r  = wm * 32 + rm * 16 + l15;
                int si = r * 64 + (kb ^ ((r & 7) << 3));
                ah[rm] = *reinterpret_cast<const bf16x8*>(XH + si);
            }
            #pragma unroll
            for (int cn = 0; cn < 8; ++cn) {
                int n  = wn * 128 + cn * 16 + l15;
                int sj = n * 64 + (kb ^ ((n & 7) << 3));
                bf16x8 bh = *reinterpret_cast<const bf16x8*>(WH + sj);
                #pragma unroll
                for (int rm = 0; rm < 2; ++rm)
                    acc[rm][cn] = __builtin_amdgcn_mfma_f32_16x16x32_bf16(
                        ah[rm], bh, acc[rm][cn], 0, 0, 0);
            }
        }
    }

    // ---- epilogue: max over i (= lane col group), bias, relu ----
    // D layout (m89/m91): col = lane&15 (= i of filter f), row = (lane>>4)*4+q.
    #pragma unroll
    for (int rm = 0; rm < 2; ++rm) {
        #pragma unroll
        for (int cn = 0; cn < 8; ++cn) {
            float mx[4];
            #pragma unroll
            for (int q = 0; q < 4; ++q) {
                float v = acc[rm][cn][q];
                v = fmaxf(v, __shfl_xor(v, 1));
                v = fmaxf(v, __shfl_xor(v, 2));
                v = fmaxf(v, __shfl_xor(v, 4));
                v = fmaxf(v, __shfl_xor(v, 8));
                mx[q] = v;
            }
            if (l15 == 0) {
                int f = wn * 8 + cn;
                float bf = bias[f];
                #pragma unroll
                for (int q = 0; q < 4; ++q) {
                    int r = wm * 32 + rm * 16 + l4 * 4 + q;
                    OUTS[r * 16 + f] = fmaxf(mx[q] + bf, 0.f);
                }
            }
        }
    }
    __syncthreads();

    // coalesced store: 512 threads x float4 = 2048 floats = 128 rows x 16 f
    {
        int e  = tid * 4;
        int r  = e >> 4;
        int f0 = e & 15;
        if (v0 + r < M)
            *reinterpret_cast<float4*>(out + (size_t)(v0 + r) * 16 + f0) =
                *reinterpret_cast<const float4*>(OUTS + e);
    }
}

extern "C" void kernel_launch(void* const* d_in, const int* in_sizes, int n_in,
                              void* d_out, int out_size, void* d_ws, size_t ws_size,
                              hipStream_t stream) {
    const float* x    = (const float*)d_in[0];
    const float* kern = (const float*)d_in[1];
    const float* bias = (const float*)d_in[2];
    float* out        = (float*)d_out;

    unsigned short* wh = (unsigned short*)d_ws;             // 65536 bf16 = 128 KB

    const int M = in_sizes[0] / 256;                        // B*V = 200000

    hipLaunchKernelGGL(build_wt, dim3(256), dim3(256), 0, stream, kern, wh);

    const int blocks = (M + 127) / 128;
    hipLaunchKernelGGL(ffconv_mfma, dim3(blocks), dim3(512), 0, stream,
                       x, wh, bias, out, M);
}

// Round 7
// 352.538 us; speedup vs baseline: 1.0569x; 1.0569x over previous
//
#include <hip/hip_runtime.h>

// FrameFiberConv as bf16 MFMA GEMM, barrier-free K-loop.
//   z[v, n=f*16+i] = sum_k x[v, k=d*16+c] * WT[n][k],  WT[n][k] = K[(d-i)&15, c, f]
//   out[v,f] = relu(max_i z[v,f*16+i] + bias[f])
// W (128 KB bf16) staged in LDS once per block; X goes global->reg directly.

typedef __attribute__((ext_vector_type(8))) short          bf16x8;
typedef __attribute__((ext_vector_type(4))) float          f32x4;
typedef __attribute__((ext_vector_type(8))) unsigned short us8;   // 16 B

__device__ __forceinline__ unsigned short f32_to_bf16(float f) {
    unsigned int u = __builtin_bit_cast(unsigned int, f);
    u += 0x7FFFu + ((u >> 16) & 1u);            // round-to-nearest-even
    return (unsigned short)(u >> 16);
}

__device__ __forceinline__ bf16x8 cvt8(float4 a, float4 b) {
    bf16x8 r;
    r[0] = (short)f32_to_bf16(a.x); r[1] = (short)f32_to_bf16(a.y);
    r[2] = (short)f32_to_bf16(a.z); r[3] = (short)f32_to_bf16(a.w);
    r[4] = (short)f32_to_bf16(b.x); r[5] = (short)f32_to_bf16(b.y);
    r[6] = (short)f32_to_bf16(b.z); r[7] = (short)f32_to_bf16(b.w);
    return r;
}

// ---- kernel 1: build WT bf16 into ws (WH[256][256], row-major) ----
__global__ __launch_bounds__(256) void build_wt(
    const float* __restrict__ kern,             // [16][16][16] (w,c,f)
    unsigned short* __restrict__ wh)
{
    int n = blockIdx.x;                         // n = f*16 + i
    int k = threadIdx.x;                        // k = d*16 + c
    int f = n >> 4, i = n & 15;
    int d = k >> 4, c = k & 15;
    int w = (d - i) & 15;
    wh[(n << 8) + k] = f32_to_bf16(kern[(w << 8) + (c << 4) + f]);
}

// ---- kernel 2: main GEMM + fused max/bias/relu ----
// 512 thr = 8 waves as 4 row-waves (32 rows) x 2 col-waves (128 cols).
// LDS: full W [256 n][256 k] bf16, swizzled k' = k ^ ((n&7)<<3) (octet XOR).
// A-fragments come straight from global (fp32) -> cvt to bf16 in registers.

#define LOADX(buf, kc) {                                                      \
    _Pragma("unroll")                                                         \
    for (int h = 0; h < 2; ++h) {                                             \
        buf[0+h] = *(const float4*)(xrow0 + (kc)*64 +  0 + l4*8 + h*4);       \
        buf[2+h] = *(const float4*)(xrow0 + (kc)*64 + 32 + l4*8 + h*4);       \
        buf[4+h] = *(const float4*)(xrow1 + (kc)*64 +  0 + l4*8 + h*4);       \
        buf[6+h] = *(const float4*)(xrow1 + (kc)*64 + 32 + l4*8 + h*4);       \
    } }

#define COMPUTE(buf, kc) {                                                    \
    bf16x8 ah00 = cvt8(buf[0], buf[1]);  /* rm0 ks0 */                        \
    bf16x8 ah01 = cvt8(buf[2], buf[3]);  /* rm0 ks1 */                        \
    bf16x8 ah10 = cvt8(buf[4], buf[5]);  /* rm1 ks0 */                        \
    bf16x8 ah11 = cvt8(buf[6], buf[7]);  /* rm1 ks1 */                        \
    _Pragma("unroll")                                                         \
    for (int ks = 0; ks < 2; ++ks) {                                          \
        _Pragma("unroll")                                                     \
        for (int cn = 0; cn < 8; ++cn) {                                      \
            int n   = wn*128 + cn*16 + l15;                                   \
            int k   = (kc)*64 + ks*32 + l4*8;                                 \
            int idx = n*256 + (k ^ ((n & 7) << 3));                           \
            bf16x8 bh = *(const bf16x8*)(WH + idx);                           \
            acc[0][cn] = __builtin_amdgcn_mfma_f32_16x16x32_bf16(             \
                ks ? ah01 : ah00, bh, acc[0][cn], 0, 0, 0);                   \
            acc[1][cn] = __builtin_amdgcn_mfma_f32_16x16x32_bf16(             \
                ks ? ah11 : ah10, bh, acc[1][cn], 0, 0, 0);                   \
        }                                                                     \
    } }

__global__ __launch_bounds__(512) void ffconv_mfma(
    const float* __restrict__ x,                // [M][256]
    const unsigned short* __restrict__ wh_g,    // [256][256] bf16
    const float* __restrict__ bias,             // [16]
    float* __restrict__ out,                    // [M][16]
    int M)
{
    __shared__ unsigned short WH[256 * 256];    // 128 KB
    __shared__ float OUTS[128 * 16];            // 8 KB

    const int tid  = threadIdx.x;
    const int lane = tid & 63;
    const int wid  = tid >> 6;
    const int wm   = wid >> 1;                  // 0..3: rows 32*wm..+32
    const int wn   = wid & 1;                   // 0..1: cols 128*wn..+128
    const int l15  = lane & 15;
    const int l4   = lane >> 4;
    const int v0   = blockIdx.x * 128;

    // row pointers (clamped; OOB rows compute garbage that is never stored)
    int r0 = v0 + wm * 32 + l15;
    int r1 = r0 + 16;
    const float* xrow0 = x + (size_t)(r0 < M ? r0 : M - 1) * 256;
    const float* xrow1 = x + (size_t)(r1 < M ? r1 : M - 1) * 256;

    f32x4 acc[2][8];
    #pragma unroll
    for (int rm = 0; rm < 2; ++rm)
        #pragma unroll
        for (int cn = 0; cn < 8; ++cn)
            acc[rm][cn] = (f32x4){0.f, 0.f, 0.f, 0.f};

    // ---- issue X loads for kc=0 first: overlap with W staging ----
    float4 xa[8], xb[8];
    LOADX(xa, 0);

    // ---- stage FULL W into LDS (once), swizzled ----
    #pragma unroll
    for (int p = 0; p < 16; ++p) {
        int e  = (p * 512 + tid) * 8;           // element 0..65535
        int n  = e >> 8;
        int k0 = e & 255;                       // 8-aligned octet
        us8 v  = *(const us8*)(wh_g + n * 256 + k0);
        int idx = n * 256 + (k0 ^ ((n & 7) << 3));
        *(us8*)(WH + idx) = v;
    }
    __syncthreads();                            // the ONLY pre-loop barrier

    // ---- barrier-free K-loop, dbuf'd raw-X registers (T14 issue-early) ----
    LOADX(xb, 1);
    COMPUTE(xa, 0);
    LOADX(xa, 2);
    COMPUTE(xb, 1);
    LOADX(xb, 3);
    COMPUTE(xa, 2);
    COMPUTE(xb, 3);

    // ---- epilogue: max over i (cols of fragment), bias, relu ----
    // D layout (m89/m91): col = lane&15 (= i of filter f), row = (lane>>4)*4+q.
    #pragma unroll
    for (int rm = 0; rm < 2; ++rm) {
        #pragma unroll
        for (int cn = 0; cn < 8; ++cn) {
            float mx[4];
            #pragma unroll
            for (int q = 0; q < 4; ++q) {
                float v = acc[rm][cn][q];
                v = fmaxf(v, __shfl_xor(v, 1));
                v = fmaxf(v, __shfl_xor(v, 2));
                v = fmaxf(v, __shfl_xor(v, 4));
                v = fmaxf(v, __shfl_xor(v, 8));
                mx[q] = v;
            }
            if (l15 == 0) {
                int f = wn * 8 + cn;
                float bf = bias[f];
                #pragma unroll
                for (int q = 0; q < 4; ++q) {
                    int r = wm * 32 + rm * 16 + l4 * 4 + q;
                    OUTS[r * 16 + f] = fmaxf(mx[q] + bf, 0.f);
                }
            }
        }
    }
    __syncthreads();

    // coalesced store: 512 threads x float4 = 128 rows x 16 f
    {
        int e  = tid * 4;
        int r  = e >> 4;
        int f0 = e & 15;
        if (v0 + r < M)
            *reinterpret_cast<float4*>(out + (size_t)(v0 + r) * 16 + f0) =
                *reinterpret_cast<const float4*>(OUTS + e);
    }
}

extern "C" void kernel_launch(void* const* d_in, const int* in_sizes, int n_in,
                              void* d_out, int out_size, void* d_ws, size_t ws_size,
                              hipStream_t stream) {
    const float* x    = (const float*)d_in[0];
    const float* kern = (const float*)d_in[1];
    const float* bias = (const float*)d_in[2];
    float* out        = (float*)d_out;

    unsigned short* wh = (unsigned short*)d_ws;             // 65536 bf16 = 128 KB

    const int M = in_sizes[0] / 256;                        // B*V = 200000

    hipLaunchKernelGGL(build_wt, dim3(256), dim3(256), 0, stream, kern, wh);

    const int blocks = (M + 127) / 128;
    hipLaunchKernelGGL(ffconv_mfma, dim3(blocks), dim3(512), 0, stream,
                       x, wh, bias, out, M);
}

// Round 10
// 320.364 us; speedup vs baseline: 1.1631x; 1.1004x over previous
//
#include <hip/hip_runtime.h>

// FrameFiberConv as bf16 MFMA GEMM — persistent blocks + asm-pinned X prefetch.
//   z[v, n=f*16+i] = sum_k x[v, k=d*16+c] * WT[n][k],  WT[n][k] = K[(d-i)&15, c, f]
//   out[v,f] = relu(max_i z[v,f*16+i] + bias[f])
// W (128 KB bf16) staged in LDS ONCE per persistent block; X global->reg via
// volatile inline-asm global_load_dwordx4 (pins 8-wide issue; compiler cannot
// collapse the buffer to 1 register like round 7's VGPR=88 showed), consumed
// under counted s_waitcnt vmcnt(N) + sched_barrier(0)  (T4 + rule #18).

typedef __attribute__((ext_vector_type(8))) short          bf16x8;
typedef __attribute__((ext_vector_type(4))) float          f32x4;
typedef __attribute__((ext_vector_type(8))) unsigned short us8;   // 16 B

__device__ __forceinline__ unsigned short f32_to_bf16(float f) {
    unsigned int u = __builtin_bit_cast(unsigned int, f);
    u += 0x7FFFu + ((u >> 16) & 1u);            // round-to-nearest-even
    return (unsigned short)(u >> 16);
}

__device__ __forceinline__ bf16x8 cvt8(f32x4 a, f32x4 b) {
    bf16x8 r;
    r[0] = (short)f32_to_bf16(a[0]); r[1] = (short)f32_to_bf16(a[1]);
    r[2] = (short)f32_to_bf16(a[2]); r[3] = (short)f32_to_bf16(a[3]);
    r[4] = (short)f32_to_bf16(b[0]); r[5] = (short)f32_to_bf16(b[1]);
    r[6] = (short)f32_to_bf16(b[2]); r[7] = (short)f32_to_bf16(b[3]);
    return r;
}

// ---- kernel 1: build WT bf16 into ws (WH[256][256], row-major) ----
__global__ __launch_bounds__(256) void build_wt(
    const float* __restrict__ kern,             // [16][16][16] (w,c,f)
    unsigned short* __restrict__ wh)
{
    int n = blockIdx.x;                         // n = f*16 + i
    int k = threadIdx.x;                        // k = d*16 + c
    int f = n >> 4, i = n & 15;
    int d = k >> 4, c = k & 15;
    int w = (d - i) & 15;
    wh[(n << 8) + k] = f32_to_bf16(kern[(w << 8) + (c << 4) + f]);
}

// pinned 16-B global load: volatile asm fixes issue point, "=v" forces a live
// distinct 4-VGPR destination. Compiler does NOT track the wait -> VMWAIT below.
#define GLD(dst, addr) \
    asm volatile("global_load_dwordx4 %0, %1, off" : "=v"(dst) : "v"(addr))

// counted wait + scheduling fence (rule #18: fence needed so dependent VALU
// cannot be hoisted above the waitcnt)
#define VMWAIT(N) do { \
    asm volatile("s_waitcnt vmcnt(" #N ")" ::: "memory"); \
    __builtin_amdgcn_sched_barrier(0); } while (0)

// issue one phase's 8 loads (2 rows x 2 k-halves x 8 floats)
#define ISSUE(buf, kc) { \
    GLD(buf[0], xrow0 + (kc)*64 +  0 + l4*8); \
    GLD(buf[1], xrow0 + (kc)*64 +  4 + l4*8); \
    GLD(buf[2], xrow0 + (kc)*64 + 32 + l4*8); \
    GLD(buf[3], xrow0 + (kc)*64 + 36 + l4*8); \
    GLD(buf[4], xrow1 + (kc)*64 +  0 + l4*8); \
    GLD(buf[5], xrow1 + (kc)*64 +  4 + l4*8); \
    GLD(buf[6], xrow1 + (kc)*64 + 32 + l4*8); \
    GLD(buf[7], xrow1 + (kc)*64 + 36 + l4*8); }

#define CVTS(buf) { \
    ah00 = cvt8(buf[0], buf[1]);   /* rm0 ks0 */ \
    ah01 = cvt8(buf[2], buf[3]);   /* rm0 ks1 */ \
    ah10 = cvt8(buf[4], buf[5]);   /* rm1 ks0 */ \
    ah11 = cvt8(buf[6], buf[7]); } /* rm1 ks1 */

#define MFMAS(kc) { \
    _Pragma("unroll") \
    for (int ks = 0; ks < 2; ++ks) { \
        _Pragma("unroll") \
        for (int cn = 0; cn < 8; ++cn) { \
            int n   = wn*128 + cn*16 + l15; \
            int k   = (kc)*64 + ks*32 + l4*8; \
            int idx = n*256 + (k ^ ((n & 7) << 3)); \
            bf16x8 bh = *(const bf16x8*)(WH + idx); \
            acc[0][cn] = __builtin_amdgcn_mfma_f32_16x16x32_bf16( \
                ks ? ah01 : ah00, bh, acc[0][cn], 0, 0, 0); \
            acc[1][cn] = __builtin_amdgcn_mfma_f32_16x16x32_bf16( \
                ks ? ah11 : ah10, bh, acc[1][cn], 0, 0, 0); \
        } } }

#define SETROWS(tt) { \
    int rr0 = (tt)*128 + wm*32 + l15; \
    int rr1 = rr0 + 16; \
    xrow0 = x + (size_t)(rr0 < M ? rr0 : M - 1) * 256; \
    xrow1 = x + (size_t)(rr1 < M ? rr1 : M - 1) * 256; }

__global__ __launch_bounds__(512, 2) void ffconv_mfma(
    const float* __restrict__ x,                // [M][256]
    const unsigned short* __restrict__ wh_g,    // [256][256] bf16
    const float* __restrict__ bias,             // [16]
    float* __restrict__ out,                    // [M][16]
    int M, int nt)                              // nt = ceil(M/128) tiles
{
    __shared__ unsigned short WH[256 * 256];    // 128 KB (1 block/CU)
    __shared__ float OUTS[128 * 16];            // 8 KB

    const int tid  = threadIdx.x;
    const int lane = tid & 63;
    const int wid  = tid >> 6;
    const int wm   = wid >> 1;                  // 0..3: rows 32*wm..+32
    const int wn   = wid & 1;                   // 0..1: cols 128*wn..+128
    const int l15  = lane & 15;
    const int l4   = lane >> 4;
    const int G    = gridDim.x;

    // hoist bias to registers (keeps the K-loop's vmem stream = only our loads)
    float bv[8];
    #pragma unroll
    for (int cn = 0; cn < 8; ++cn) bv[cn] = bias[wn * 8 + cn];

    const float *xrow0, *xrow1;
    f32x4 xa[8], xb[8];
    f32x4 acc[2][8];
    bf16x8 ah00, ah01, ah10, ah11;

    // ---- prologue: issue first tile's loads, then stage W (latency overlap) ----
    SETROWS(blockIdx.x);
    ISSUE(xa, 0);
    ISSUE(xb, 1);

    #pragma unroll
    for (int p = 0; p < 16; ++p) {
        int e  = (p * 512 + tid) * 8;           // element 0..65535
        int n  = e >> 8;
        int k0 = e & 255;                       // 8-aligned octet
        us8 v  = *(const us8*)(wh_g + n * 256 + k0);
        int idx = n * 256 + (k0 ^ ((n & 7) << 3));
        *(us8*)(WH + idx) = v;
    }
    __syncthreads();   // compiler drains vmcnt(0) here -> prologue loads done

    // ---- persistent tile loop ----
    for (int t = blockIdx.x; t < nt; t += G) {
        #pragma unroll
        for (int rm = 0; rm < 2; ++rm)
            #pragma unroll
            for (int cn = 0; cn < 8; ++cn)
                acc[rm][cn] = (f32x4){0.f, 0.f, 0.f, 0.f};

        // phase 0: consume xa(kc0); refill xa with kc2 right after cvt
        VMWAIT(8);  CVTS(xa);  ISSUE(xa, 2);  MFMAS(0);
        // phase 1: consume xb(kc1); refill xb with kc3
        VMWAIT(8);  CVTS(xb);  ISSUE(xb, 3);  MFMAS(1);
        // phase 2: consume xa(kc2)
        VMWAIT(8);  CVTS(xa);  MFMAS(2);
        // phase 3: consume xb(kc3); issue NEXT tile's kc0/kc1 before MFMAs
        VMWAIT(0);  CVTS(xb);
        {
            int tn = t + G;
            if (tn < nt) { SETROWS(tn); ISSUE(xa, 0); ISSUE(xb, 1); }
        }
        MFMAS(3);

        // ---- epilogue: max over i (cols of fragment), bias, relu ----
        // D layout (m89/m91): col = lane&15 (= i of filter f), row=(lane>>4)*4+q
        #pragma unroll
        for (int rm = 0; rm < 2; ++rm) {
            #pragma unroll
            for (int cn = 0; cn < 8; ++cn) {
                float mx[4];
                #pragma unroll
                for (int q = 0; q < 4; ++q) {
                    float v = acc[rm][cn][q];
                    v = fmaxf(v, __shfl_xor(v, 1));
                    v = fmaxf(v, __shfl_xor(v, 2));
                    v = fmaxf(v, __shfl_xor(v, 4));
                    v = fmaxf(v, __shfl_xor(v, 8));
                    mx[q] = v;
                }
                if (l15 == 0) {
                    int f = wn * 8 + cn;
                    #pragma unroll
                    for (int q = 0; q < 4; ++q) {
                        int r = wm * 32 + rm * 16 + l4 * 4 + q;
                        OUTS[r * 16 + f] = fmaxf(mx[q] + bv[cn], 0.f);
                    }
                }
            }
        }
        __syncthreads();

        // coalesced store: 512 threads x float4 = 128 rows x 16 f
        {
            int e  = tid * 4;
            int r  = e >> 4;
            int f0 = e & 15;
            int v0 = t * 128;
            if (v0 + r < M)
                *reinterpret_cast<float4*>(out + (size_t)(v0 + r) * 16 + f0) =
                    *reinterpret_cast<const float4*>(OUTS + e);
        }
        __syncthreads();   // OUTS reusable next tile
    }
}

extern "C" void kernel_launch(void* const* d_in, const int* in_sizes, int n_in,
                              void* d_out, int out_size, void* d_ws, size_t ws_size,
                              hipStream_t stream) {
    const float* x    = (const float*)d_in[0];
    const float* kern = (const float*)d_in[1];
    const float* bias = (const float*)d_in[2];
    float* out        = (float*)d_out;

    unsigned short* wh = (unsigned short*)d_ws;             // 65536 bf16 = 128 KB

    const int M  = in_sizes[0] / 256;                       // B*V = 200000
    const int nt = (M + 127) / 128;                         // 1563 tiles

    hipLaunchKernelGGL(build_wt, dim3(256), dim3(256), 0, stream, kern, wh);

    // persistent: 1 block per CU (LDS 136 KB caps at 1 anyway)
    hipLaunchKernelGGL(ffconv_mfma, dim3(256), dim3(512), 0, stream,
                       x, wh, bias, out, M, nt);
}